// Round 13
// baseline (394.547 us; speedup 1.0000x reference)
//
#include <hip/hip_runtime.h>
#include <hip/hip_bf16.h>
#include <stdint.h>

// ---------------------------------------------------------------------------
// MLA forward on MI355X. Round 13:
//  - attn: V LDS staging DELETED (V is L2/L1-resident per XCD) — PV A-frags
//    loaded direct from global into regs right after the barrier; LDS pipe
//    (the measured bottleneck: ~210KB/block-iter ≈ 110us) drops ~40%.
//  - rest: r12 pipeline unchanged (best-known 351us).
// ---------------------------------------------------------------------------

typedef short bf16x8 __attribute__((ext_vector_type(8)));
typedef float f32x4  __attribute__((ext_vector_type(4)));
typedef unsigned int u32;

#define RMS_EPS 1.1920929e-07f
// (1/sqrt(192)) * log2(e)
#define SCALE_L2E 0.10411931095f

__device__ __forceinline__ unsigned short f2b(float f) {
  union { float f; uint32_t u; } c; c.f = f;
  uint32_t u = c.u;
  return (unsigned short)((u + 0x7FFFu + ((u >> 16) & 1u)) >> 16);
}
__device__ __forceinline__ float b2f(short s) {
  union { uint32_t u; float f; } c; c.u = ((uint32_t)(unsigned short)s) << 16;
  return c.f;
}
__device__ __forceinline__ u32 pk2(float a, float b) {
  union { __hip_bfloat162 h; u32 u; } cv;
  cv.h = __float22bfloat162_rn(float2{a, b});
  return cv.u;
}
__device__ __forceinline__ void gld16(const short* g, short* l) {
  __builtin_amdgcn_global_load_lds(
      (const __attribute__((address_space(1))) u32*)g,
      (__attribute__((address_space(3))) u32*)l, 16, 0, 0);
}

__device__ __forceinline__ void cvt4(const float* __restrict__ in,
                                     short* __restrict__ out, int i) {
  float4 v = ((const float4*)in)[i];
  union { ushort4 s; uint2 u; } o;
  o.s.x = f2b(v.x); o.s.y = f2b(v.y); o.s.z = f2b(v.z); o.s.w = f2b(v.w);
  ((uint2*)out)[i] = o.u;
}

// ---------------- merged fp32 -> bf16 conversion (all segments) --------------
__global__ void f2bf_all_kernel(
    const float* __restrict__ x,    short* __restrict__ x_bf,
    const float* __restrict__ Wqd,  short* __restrict__ w_qd,
    const float* __restrict__ Wqu,  short* __restrict__ w_qu,
    const float* __restrict__ Wkvu, short* __restrict__ w_kvu,
    const float* __restrict__ Wo,   short* __restrict__ w_o,
    const float* __restrict__ Wkvd, short* __restrict__ w_kvd) {
  int i = blockIdx.x * 256 + threadIdx.x;
  if (i < 2097152) { cvt4(x, x_bf, i); return; }
  i -= 2097152;
  if (i < 786432) { cvt4(Wqd, w_qd, i); return; }
  i -= 786432;
  if (i < 1179648) { cvt4(Wqu, w_qu, i); return; }
  i -= 1179648;
  if (i < 524288) { cvt4(Wkvu, w_kvu, i); return; }
  i -= 524288;
  if (i < 1048576) { cvt4(Wo, w_o, i); return; }
  i -= 1048576;
  if (i >= 327680) return;
  int row = i >> 9;  // 512 f4 per row
  ushort4 s = {0, 0, 0, 0};
  if (row < 576) {
    float4 v = ((const float4*)Wkvd)[i];
    s.x = f2b(v.x); s.y = f2b(v.y); s.z = f2b(v.z); s.w = f2b(v.w);
  }
  union { ushort4 ss; uint2 u; } o; o.ss = s;
  ((uint2*)w_kvd)[i] = o.u;
}

// ---------------- GEMM body (shared by all launches) -------------------------
// EPI 0/1/2 compute C^T fragments (mfma(b,a)); EPI 3 original orientation.
template <int EPI>
__device__ __forceinline__ void gemm_body(
    short* As, short* Bs, int row0, int col0,
    const short* __restrict__ A, const short* __restrict__ Bt,
    void* __restrict__ Cv, const float* __restrict__ bias,
    int K, int ldc,
    const float* __restrict__ fc, const float* __restrict__ fs,
    short* __restrict__ aux) {
  int t = threadIdx.x, lane = t & 63, w = t >> 6;
  int wm = w >> 1, wn = w & 1;
  int l15 = lane & 15, l4 = lane >> 4;
  f32x4 acc[4][4] = {};

  int srow = lane >> 2, scol = (lane & 3) * 8;
  const short* Ag = A + (size_t)(row0 + srow) * K + scol;
  const short* Bg = Bt + (size_t)(col0 + srow) * K + scol;

  for (int kt = 0; kt < K; kt += 32) {
#pragma unroll
    for (int c = 0; c < 2; ++c) {
      int blk = w * 2 + c;
      gld16(Ag + (size_t)(blk * 16) * K + kt, As + blk * 512);
      gld16(Bg + (size_t)(blk * 16) * K + kt, Bs + blk * 512);
    }
    __syncthreads();
    bf16x8 af[4], bfr[4];
#pragma unroll
    for (int i = 0; i < 4; ++i) {
      af[i]  = *(const bf16x8*)(As + (wm * 64 + i * 16 + l15) * 32 + l4 * 8);
      bfr[i] = *(const bf16x8*)(Bs + (wn * 64 + i * 16 + l15) * 32 + l4 * 8);
    }
#pragma unroll
    for (int i = 0; i < 4; ++i)
#pragma unroll
      for (int j = 0; j < 4; ++j) {
        if constexpr (EPI == 3)
          acc[i][j] = __builtin_amdgcn_mfma_f32_16x16x32_bf16(af[i], bfr[j], acc[i][j], 0, 0, 0);
        else
          acc[i][j] = __builtin_amdgcn_mfma_f32_16x16x32_bf16(bfr[j], af[i], acc[i][j], 0, 0, 0);
      }
    __syncthreads();
  }

  if constexpr (EPI == 0) {
    float* C = (float*)Cv;
#pragma unroll
    for (int i = 0; i < 4; ++i) {
      int row = row0 + wm * 64 + i * 16 + l15;
#pragma unroll
      for (int j = 0; j < 4; ++j) {
        int coln = col0 + wn * 64 + j * 16 + l4 * 4;
        float4 bv = {0.f, 0.f, 0.f, 0.f};
        if (bias) bv = *(const float4*)(bias + coln);
        float4 o;
        o.x = acc[i][j][0] + bv.x; o.y = acc[i][j][1] + bv.y;
        o.z = acc[i][j][2] + bv.z; o.w = acc[i][j][3] + bv.w;
        *(float4*)(C + (size_t)row * ldc + coln) = o;
      }
    }
  } else if constexpr (EPI == 1) {
    short* C = (short*)Cv;
#pragma unroll
    for (int i = 0; i < 4; ++i) {
      int row = row0 + wm * 64 + i * 16 + l15;
#pragma unroll
      for (int j = 0; j < 4; ++j) {
        int coln = col0 + wn * 64 + j * 16 + l4 * 4;
        uint2 o;
        o.x = pk2(acc[i][j][0], acc[i][j][1]);
        o.y = pk2(acc[i][j][2], acc[i][j][3]);
        *(uint2*)(C + (size_t)row * ldc + coln) = o;
      }
    }
  } else if constexpr (EPI == 2) {
    short* qb = (short*)Cv;
#pragma unroll
    for (int i = 0; i < 4; ++i) {
      int row = row0 + wm * 64 + i * 16 + l15;
      int b = row >> 11, s = row & 2047;
#pragma unroll
      for (int j = 0; j < 4; ++j) {
        int coln = col0 + wn * 64 + j * 16 + l4 * 4;
        int h = coln / 192;
        int d0 = coln - h * 192;
        float v0 = acc[i][j][0], v1 = acc[i][j][1];
        float v2 = acc[i][j][2], v3 = acc[i][j][3];
        float o0, o1, o2, o3;
        if (d0 >= 128) {
          int ir0 = (d0 - 128) >> 1;
          float c0 = fc[s * 32 + ir0], s0 = fs[s * 32 + ir0];
          float c1 = fc[s * 32 + ir0 + 1], s1 = fs[s * 32 + ir0 + 1];
          o0 = v0 * c0 - v1 * s0; o1 = v0 * s0 + v1 * c0;
          o2 = v2 * c1 - v3 * s1; o3 = v2 * s1 + v3 * c1;
        } else {
          o0 = v0; o1 = v1; o2 = v2; o3 = v3;
        }
        uint2 o;
        o.x = pk2(o0 * SCALE_L2E, o1 * SCALE_L2E);
        o.y = pk2(o2 * SCALE_L2E, o3 * SCALE_L2E);
        *(uint2*)(qb + ((size_t)((b * 16 + h) * 2048 + s)) * 192 + d0) = o;
      }
    }
  } else {  // EPI == 3
    short* kb = (short*)Cv;
    short* vT = aux;
    int h = col0 >> 8;
    if ((col0 & 128) == 0) {
#pragma unroll
      for (int j = 0; j < 4; ++j) {
        int d = wn * 64 + j * 16 + l15;
#pragma unroll
        for (int i = 0; i < 4; ++i) {
          int rowb = row0 + wm * 64 + i * 16 + l4 * 4;
#pragma unroll
          for (int r = 0; r < 4; ++r) {
            int row = rowb + r;
            int b = row >> 11, s = row & 2047;
            kb[((size_t)((b * 16 + h) * 2048 + s)) * 128 + d] = (short)f2b(acc[i][j][r]);
          }
        }
      }
    } else {
#pragma unroll
      for (int j = 0; j < 4; ++j) {
        int dv = wn * 64 + j * 16 + l15;
#pragma unroll
        for (int i = 0; i < 4; ++i) {
          int s0 = row0 + wm * 64 + i * 16 + l4 * 4;
          int b = s0 >> 11, s = s0 & 2047;
          short4 o;
          o.x = (short)f2b(acc[i][j][0]);
          o.y = (short)f2b(acc[i][j][1]);
          o.z = (short)f2b(acc[i][j][2]);
          o.w = (short)f2b(acc[i][j][3]);
          *(short4*)(vT + ((size_t)((b * 16 + h) * 128 + dv)) * 2048 + s) = o;
        }
      }
    }
  }
}

template <int EPI>
__global__ __launch_bounds__(256) void gemm_bt(
    const short* __restrict__ A, const short* __restrict__ Bt,
    void* __restrict__ Cv, const float* __restrict__ bias,
    int K, int ldc,
    const float* __restrict__ fc, const float* __restrict__ fs,
    short* __restrict__ aux) {
  __shared__ __align__(16) short As[128 * 32];
  __shared__ __align__(16) short Bs[128 * 32];
  int nx = gridDim.x;
  int lin = blockIdx.y * nx + blockIdx.x;
  int cpx = (nx * gridDim.y) >> 3;
  int swz = (lin & 7) * cpx + (lin >> 3);
  int row0 = (swz / nx) * 128, col0 = (swz % nx) * 128;
  gemm_body<EPI>(As, Bs, row0, col0, A, Bt, Cv, bias, K, ldc, fc, fs, aux);
}

// merged up-projections: blocks [0,768) = G2 (q rope), [768,1792) = G4 (kv).
__global__ __launch_bounds__(256) void gemm_up(
    const short* __restrict__ qn, const short* __restrict__ wqu,
    short* __restrict__ q_b,
    const short* __restrict__ ckvn, const short* __restrict__ wkvu,
    short* __restrict__ k_b, short* __restrict__ vT,
    const float* __restrict__ fc, const float* __restrict__ fs) {
  __shared__ __align__(16) short As[128 * 32];
  __shared__ __align__(16) short Bs[128 * 32];
  int bb = blockIdx.x;
  if (bb < 768) {
    int cpx = 768 >> 3;
    int swz = (bb & 7) * cpx + (bb >> 3);
    int row0 = (swz / 24) * 128, col0 = (swz % 24) * 128;
    gemm_body<2>(As, Bs, row0, col0, qn, wqu, q_b, nullptr, 1536, 0, fc, fs, nullptr);
  } else {
    int bb2 = bb - 768;
    int cpx = 1024 >> 3;
    int swz = (bb2 & 7) * cpx + (bb2 >> 3);
    int row0 = (swz / 32) * 128, col0 = (swz % 32) * 128;
    gemm_body<3>(As, Bs, row0, col0, ckvn, wkvu, k_b, nullptr, 512, 0, nullptr, nullptr, vT);
  }
}

// ---------------- merged rmsnorm(q) + rmsnorm(kv) + krope --------------------
template <int W>
__device__ __forceinline__ void rms_body(
    const short* __restrict__ in, const float* __restrict__ wgt,
    short* __restrict__ out, int ld_in, int blk) {
  constexpr int NC = W / 512;
  int row = blk * 4 + (threadIdx.x >> 6);
  int lane = threadIdx.x & 63;
  const short* x = in + (size_t)row * ld_in + lane * 8;
  float vals[NC * 8];
  float ss = 0.f;
#pragma unroll
  for (int c = 0; c < NC; ++c) {
    bf16x8 v = *(const bf16x8*)(x + c * 512);
#pragma unroll
    for (int k = 0; k < 8; ++k) {
      float f = b2f(v[k]);
      vals[c * 8 + k] = f; ss += f * f;
    }
  }
#pragma unroll
  for (int off = 32; off > 0; off >>= 1) ss += __shfl_xor(ss, off);
  float rs = rsqrtf(ss / (float)W + RMS_EPS);
  short* o = out + (size_t)row * W + lane * 8;
#pragma unroll
  for (int c = 0; c < NC; ++c) {
    const float4* wp = (const float4*)(wgt + c * 512 + lane * 8);
    float4 w0 = wp[0], w1 = wp[1];
    ushort4 lo, hi;
    lo.x = f2b(vals[c * 8 + 0] * rs * w0.x);
    lo.y = f2b(vals[c * 8 + 1] * rs * w0.y);
    lo.z = f2b(vals[c * 8 + 2] * rs * w0.z);
    lo.w = f2b(vals[c * 8 + 3] * rs * w0.w);
    hi.x = f2b(vals[c * 8 + 4] * rs * w1.x);
    hi.y = f2b(vals[c * 8 + 5] * rs * w1.y);
    hi.z = f2b(vals[c * 8 + 6] * rs * w1.z);
    hi.w = f2b(vals[c * 8 + 7] * rs * w1.w);
    *(ushort4*)(o + c * 512) = lo;
    *(ushort4*)(o + c * 512 + 4) = hi;
  }
}

__global__ __launch_bounds__(256) void norm_krope_kernel(
    const short* __restrict__ c1,
    const float* __restrict__ qnw, short* __restrict__ qn,
    const float* __restrict__ kvnw, short* __restrict__ ckvn,
    const float* __restrict__ fc, const float* __restrict__ fs,
    short* __restrict__ kr) {
  int bb = blockIdx.x;
  if (bb < 1024) {
    rms_body<1536>(c1, qnw, qn, 2176, bb);
  } else if (bb < 2048) {
    rms_body<512>(c1 + 1600, kvnw, ckvn, 2176, bb - 1024);
  } else {
    int idx = (bb - 2048) * 256 + threadIdx.x;  // B*S*32 = 131072
    int i = idx & 31;
    int s = (idx >> 5) & 2047;
    int b = idx >> 16;
    const short* row = c1 + (size_t)(b * 2048 + s) * 2176 + 1536 + 2 * i;
    float x0 = b2f(row[0]), x1 = b2f(row[1]);
    float c = fc[s * 32 + i], sn = fs[s * 32 + i];
    uint32_t pk = (uint32_t)f2b(x0 * c - x1 * sn) | ((uint32_t)f2b(x0 * sn + x1 * c) << 16);
    *(uint32_t*)(kr + ((size_t)(b * 2048 + s)) * 64 + 2 * i) = pk;
  }
}

// ---------------- flash attention (K in LDS, V direct from L2/L1) ------------
// grid 512; XCD remap, paired q-tiles {qx, 31-qx} => uniform 33 iters/block.
// K prefetched to regs then LDS; V A-frags loaded straight from global into
// named regs after the barrier (land under QK+softmax) — no Vs buffer.
__global__ __launch_bounds__(256, 2) void attn_kernel(
    const short* __restrict__ qb, const short* __restrict__ kb,
    const short* __restrict__ kr, const short* __restrict__ vtb,
    short* __restrict__ ob) {
  __shared__ __align__(16) short Ks[64 * 196];
  int bid = blockIdx.x;
  int xcd = bid & 7, kk2 = bid >> 3;       // kk2: 0..63
  int bh = xcd * 4 + (kk2 >> 4);           // 4 bh per XCD
  int qx = kk2 & 15;
  int b = bh >> 4, h = bh & 15;
  int t = threadIdx.x, lane = t & 63, w = t >> 6;
  int l15 = lane & 15, l4 = lane >> 4;
  const short* Kbh = kb + (size_t)bh * 2048 * 128;
  const short* krb = kr + (size_t)b * 2048 * 64;
  const short* Vbh = vtb + (size_t)bh * 128 * 2048;
  const short* Vlane = Vbh + (size_t)l15 * 2048 + l4 * 8;  // + dt*32768 + kt (+32)

  // non-divergent staging geometry
  int kn_r = t >> 4, kn_c = (t & 15) * 8;          // nope: 4 chunks of 16 rows
  int kr_r = t >> 3, kr_c = (t & 7) * 8;           // rope: 2 chunks of 32 rows

  // bpermute source lanes for P redistribution (byte addr = lane*4)
  int sA = (l15 + ((l4 & 1) << 5)) << 2;
  int sB = sA + (16 << 2);
  bool chi = (l4 >> 1) != 0;

  for (int half = 0; half < 2; ++half) {
    int qt = half ? (31 - qx) : qx;
    int q0 = qt * 64;
    const short* Qbase = qb + ((size_t)bh * 2048 + q0 + w * 16) * 192;
    bf16x8 qf[6];
#pragma unroll
    for (int kk = 0; kk < 6; ++kk)
      qf[kk] = *(const bf16x8*)(Qbase + (size_t)l15 * 192 + kk * 32 + l4 * 8);
    f32x4 oaccT[8] = {};
    float m_i = -1e30f, l_i = 0.f;
    int qcol = q0 + w * 16 + l15;
    int kend = q0 + 64;

    // prefetch K tile 0 into registers
    bf16x8 pn0, pn1, pn2, pn3, pr0, pr1;
    pn0 = *(const bf16x8*)(Kbh + (size_t)(kn_r) * 128 + kn_c);
    pn1 = *(const bf16x8*)(Kbh + (size_t)(kn_r + 16) * 128 + kn_c);
    pn2 = *(const bf16x8*)(Kbh + (size_t)(kn_r + 32) * 128 + kn_c);
    pn3 = *(const bf16x8*)(Kbh + (size_t)(kn_r + 48) * 128 + kn_c);
    pr0 = *(const bf16x8*)(krb + (size_t)(kr_r) * 64 + kr_c);
    pr1 = *(const bf16x8*)(krb + (size_t)(kr_r + 32) * 64 + kr_c);

    for (int kt = 0; kt < kend; kt += 64) {
      // write prefetched K tile to LDS
      *(bf16x8*)(Ks + (kn_r) * 196 + kn_c) = pn0;
      *(bf16x8*)(Ks + (kn_r + 16) * 196 + kn_c) = pn1;
      *(bf16x8*)(Ks + (kn_r + 32) * 196 + kn_c) = pn2;
      *(bf16x8*)(Ks + (kn_r + 48) * 196 + kn_c) = pn3;
      *(bf16x8*)(Ks + (kr_r) * 196 + 128 + kr_c) = pr0;
      *(bf16x8*)(Ks + (kr_r + 32) * 196 + 128 + kr_c) = pr1;
      __syncthreads();
      // V A-frags for THIS tile: direct from global (L2/L1-resident), issued
      // now so they land under QK + softmax.
      bf16x8 v0a, v0b, v1a, v1b, v2a, v2b, v3a, v3b;
      bf16x8 v4a, v4b, v5a, v5b, v6a, v6b, v7a, v7b;
      {
        const short* vp = Vlane + kt;
        v0a = *(const bf16x8*)(vp);            v0b = *(const bf16x8*)(vp + 32);
        v1a = *(const bf16x8*)(vp + 32768);    v1b = *(const bf16x8*)(vp + 32800);
        v2a = *(const bf16x8*)(vp + 65536);    v2b = *(const bf16x8*)(vp + 65568);
        v3a = *(const bf16x8*)(vp + 98304);    v3b = *(const bf16x8*)(vp + 98336);
        v4a = *(const bf16x8*)(vp + 131072);   v4b = *(const bf16x8*)(vp + 131104);
        v5a = *(const bf16x8*)(vp + 163840);   v5b = *(const bf16x8*)(vp + 163872);
        v6a = *(const bf16x8*)(vp + 196608);   v6b = *(const bf16x8*)(vp + 196640);
        v7a = *(const bf16x8*)(vp + 229376);   v7b = *(const bf16x8*)(vp + 229408);
      }
      // issue NEXT K tile's loads — fly under this tile's compute.
      if (kt + 64 < kend) {
        int k2 = kt + 64;
        pn0 = *(const bf16x8*)(Kbh + (size_t)(k2 + kn_r) * 128 + kn_c);
        pn1 = *(const bf16x8*)(Kbh + (size_t)(k2 + kn_r + 16) * 128 + kn_c);
        pn2 = *(const bf16x8*)(Kbh + (size_t)(k2 + kn_r + 32) * 128 + kn_c);
        pn3 = *(const bf16x8*)(Kbh + (size_t)(k2 + kn_r + 48) * 128 + kn_c);
        pr0 = *(const bf16x8*)(krb + (size_t)(k2 + kr_r) * 64 + kr_c);
        pr1 = *(const bf16x8*)(krb + (size_t)(k2 + kr_r + 32) * 64 + kr_c);
      }

      // S^T: A = K rows, B = Q cols
      f32x4 s[4] = {};
      __builtin_amdgcn_s_setprio(1);
#pragma unroll
      for (int kk = 0; kk < 6; ++kk) {
#pragma unroll
        for (int c = 0; c < 4; ++c) {
          bf16x8 kf = *(const bf16x8*)(Ks + (c * 16 + l15) * 196 + kk * 32 + l4 * 8);
          s[c] = __builtin_amdgcn_mfma_f32_16x16x32_bf16(kf, qf[kk], s[c], 0, 0, 0);
        }
      }
      __builtin_amdgcn_s_setprio(0);

      if (kt == q0) {  // diagonal tile: mask k > q
#pragma unroll
        for (int c = 0; c < 4; ++c)
#pragma unroll
          for (int r = 0; r < 4; ++r) {
            int k = kt + c * 16 + l4 * 4 + r;
            if (k > qcol) s[c][r] = -1e30f;
          }
      }
      // per-q softmax: in-lane over 16 + cross-group (xor 16, 32)
      float mx = fmaxf(fmaxf(fmaxf(s[0][0], s[0][1]), fmaxf(s[0][2], s[0][3])),
                       fmaxf(fmaxf(s[1][0], s[1][1]), fmaxf(s[1][2], s[1][3])));
      mx = fmaxf(mx, fmaxf(fmaxf(fmaxf(s[2][0], s[2][1]), fmaxf(s[2][2], s[2][3])),
                           fmaxf(fmaxf(s[3][0], s[3][1]), fmaxf(s[3][2], s[3][3]))));
      mx = fmaxf(mx, __shfl_xor(mx, 16));
      mx = fmaxf(mx, __shfl_xor(mx, 32));
      float newm = fmaxf(m_i, mx);
      float alpha = __builtin_amdgcn_exp2f(m_i - newm);
      float rs = 0.f;
#pragma unroll
      for (int c = 0; c < 4; ++c)
#pragma unroll
        for (int r = 0; r < 4; ++r) {
          float p = __builtin_amdgcn_exp2f(s[c][r] - newm);
          s[c][r] = p; rs += p;
        }
      rs += __shfl_xor(rs, 16);
      rs += __shfl_xor(rs, 32);
      l_i = l_i * alpha + rs;
      m_i = newm;
#pragma unroll
      for (int dt = 0; dt < 8; ++dt)
#pragma unroll
        for (int r = 0; r < 4; ++r) oaccT[dt][r] *= alpha;

      // pack P^T to bf16 pairs (named regs; no runtime indexing)
      u32 pk00 = pk2(s[0][0], s[0][1]), pk01 = pk2(s[0][2], s[0][3]);
      u32 pk10 = pk2(s[1][0], s[1][1]), pk11 = pk2(s[1][2], s[1][3]);
      u32 pk20 = pk2(s[2][0], s[2][1]), pk21 = pk2(s[2][2], s[2][3]);
      u32 pk30 = pk2(s[3][0], s[3][1]), pk31 = pk2(s[3][2], s[3][3]);
      union { bf16x8 v; u32 u[4]; } P0, P1;
      {
        u32 a0 = __builtin_amdgcn_ds_bpermute(sA, (int)pk00);
        u32 a1 = __builtin_amdgcn_ds_bpermute(sA, (int)pk01);
        u32 a2 = __builtin_amdgcn_ds_bpermute(sB, (int)pk00);
        u32 a3 = __builtin_amdgcn_ds_bpermute(sB, (int)pk01);
        u32 b0 = __builtin_amdgcn_ds_bpermute(sA, (int)pk10);
        u32 b1 = __builtin_amdgcn_ds_bpermute(sA, (int)pk11);
        u32 b2 = __builtin_amdgcn_ds_bpermute(sB, (int)pk10);
        u32 b3 = __builtin_amdgcn_ds_bpermute(sB, (int)pk11);
        P0.u[0] = chi ? b0 : a0; P0.u[1] = chi ? b1 : a1;
        P0.u[2] = chi ? b2 : a2; P0.u[3] = chi ? b3 : a3;
      }
      {
        u32 a0 = __builtin_amdgcn_ds_bpermute(sA, (int)pk20);
        u32 a1 = __builtin_amdgcn_ds_bpermute(sA, (int)pk21);
        u32 a2 = __builtin_amdgcn_ds_bpermute(sB, (int)pk20);
        u32 a3 = __builtin_amdgcn_ds_bpermute(sB, (int)pk21);
        u32 b0 = __builtin_amdgcn_ds_bpermute(sA, (int)pk30);
        u32 b1 = __builtin_amdgcn_ds_bpermute(sA, (int)pk31);
        u32 b2 = __builtin_amdgcn_ds_bpermute(sB, (int)pk30);
        u32 b3 = __builtin_amdgcn_ds_bpermute(sB, (int)pk31);
        P1.u[0] = chi ? b0 : a0; P1.u[1] = chi ? b1 : a1;
        P1.u[2] = chi ? b2 : a2; P1.u[3] = chi ? b3 : a3;
      }

      // O^T += V^T-frag x P^T-frag (V frags already in regs)
      __builtin_amdgcn_s_setprio(1);
      oaccT[0] = __builtin_amdgcn_mfma_f32_16x16x32_bf16(v0a, P0.v, oaccT[0], 0, 0, 0);
      oaccT[0] = __builtin_amdgcn_mfma_f32_16x16x32_bf16(v0b, P1.v, oaccT[0], 0, 0, 0);
      oaccT[1] = __builtin_amdgcn_mfma_f32_16x16x32_bf16(v1a, P0.v, oaccT[1], 0, 0, 0);
      oaccT[1] = __builtin_amdgcn_mfma_f32_16x16x32_bf16(v1b, P1.v, oaccT[1], 0, 0, 0);
      oaccT[2] = __builtin_amdgcn_mfma_f32_16x16x32_bf16(v2a, P0.v, oaccT[2], 0, 0, 0);
      oaccT[2] = __builtin_amdgcn_mfma_f32_16x16x32_bf16(v2b, P1.v, oaccT[2], 0, 0, 0);
      oaccT[3] = __builtin_amdgcn_mfma_f32_16x16x32_bf16(v3a, P0.v, oaccT[3], 0, 0, 0);
      oaccT[3] = __builtin_amdgcn_mfma_f32_16x16x32_bf16(v3b, P1.v, oaccT[3], 0, 0, 0);
      oaccT[4] = __builtin_amdgcn_mfma_f32_16x16x32_bf16(v4a, P0.v, oaccT[4], 0, 0, 0);
      oaccT[4] = __builtin_amdgcn_mfma_f32_16x16x32_bf16(v4b, P1.v, oaccT[4], 0, 0, 0);
      oaccT[5] = __builtin_amdgcn_mfma_f32_16x16x32_bf16(v5a, P0.v, oaccT[5], 0, 0, 0);
      oaccT[5] = __builtin_amdgcn_mfma_f32_16x16x32_bf16(v5b, P1.v, oaccT[5], 0, 0, 0);
      oaccT[6] = __builtin_amdgcn_mfma_f32_16x16x32_bf16(v6a, P0.v, oaccT[6], 0, 0, 0);
      oaccT[6] = __builtin_amdgcn_mfma_f32_16x16x32_bf16(v6b, P1.v, oaccT[6], 0, 0, 0);
      oaccT[7] = __builtin_amdgcn_mfma_f32_16x16x32_bf16(v7a, P0.v, oaccT[7], 0, 0, 0);
      oaccT[7] = __builtin_amdgcn_mfma_f32_16x16x32_bf16(v7b, P1.v, oaccT[7], 0, 0, 0);
      __builtin_amdgcn_s_setprio(0);
      __syncthreads();
    }
    // epilogue: lane holds O^T[d = dt*16 + l4*4 + r][q = qcol]
    float inv = 1.0f / l_i;
    short* dst = ob + ((size_t)(b * 2048 + qcol)) * 2048 + h * 128;
#pragma unroll
    for (int dt = 0; dt < 8; ++dt) {
      uint2 o;
      o.x = pk2(oaccT[dt][0] * inv, oaccT[dt][1] * inv);
      o.y = pk2(oaccT[dt][2] * inv, oaccT[dt][3] * inv);
      *(uint2*)(dst + dt * 16 + l4 * 4) = o;
    }
  }
}

// ---------------------------------------------------------------------------
extern "C" void kernel_launch(void* const* d_in, const int* in_sizes, int n_in,
                              void* d_out, int out_size, void* d_ws, size_t ws_size,
                              hipStream_t stream) {
  const float* x    = (const float*)d_in[0];
  const float* fcos = (const float*)d_in[1];
  const float* fsin = (const float*)d_in[2];
  const float* Wqd  = (const float*)d_in[3];
  const float* qnw  = (const float*)d_in[4];
  const float* Wqu  = (const float*)d_in[5];
  const float* Wkvd = (const float*)d_in[6];
  const float* kvnw = (const float*)d_in[7];
  const float* Wkvu = (const float*)d_in[8];
  const float* Wo   = (const float*)d_in[9];
  const float* bo   = (const float*)d_in[10];
  float* out = (float*)d_out;
  char* ws = (char*)d_ws;

  short* x_bf  = (short*)(ws + 0);           // 4096x2048 bf16
  short* w_cat = (short*)(ws + 16777216);    // 2176x2048 (Wqd;Wkvd pad)
  short* w_qu  = (short*)(ws + 25690112);    // 3072x1536
  short* w_kvu = (short*)(ws + 35127296);    // 4096x512
  short* w_o   = (short*)(ws + 39321600);    // 2048x2048
  short* c1    = (short*)(ws + 47710208);    // 4096x2176 bf16 (qdown|krope|ckv)
  short* qn    = (short*)(ws + 65536000);    // 4096x1536 bf16
  short* ckvn  = (short*)(ws + 78118912);    // 4096x512 bf16
  short* q_b   = (short*)(ws + 82313216);    // (B,H,S,192) bf16
  short* k_b   = (short*)(ws + 107479040);   // (B,H,S,128) bf16 (nope only)
  short* vT    = (short*)(ws + 132644864);   // (B,H,128,S) bf16
  short* o_bf  = (short*)(ws + 149422080);   // (B,S,2048) bf16
  short* kr    = (short*)(ws + 166199296);   // (B,S,64) bf16 roped shared k

  f2bf_all_kernel<<<23296, 256, 0, stream>>>(x, x_bf, Wqd, w_cat, Wqu, w_qu,
                                             Wkvu, w_kvu, Wo, w_o,
                                             Wkvd, w_cat + 1536 * 2048);

  gemm_bt<1><<<dim3(17, 32), 256, 0, stream>>>(x_bf, w_cat, c1, nullptr, 2048, 2176,
                                               nullptr, nullptr, nullptr);
  norm_krope_kernel<<<2560, 256, 0, stream>>>(c1, qnw, qn, kvnw, ckvn,
                                              fcos, fsin, kr);

  gemm_up<<<1792, 256, 0, stream>>>(qn, w_qu, q_b, ckvn, w_kvu, k_b, vT,
                                    fcos, fsin);

  attn_kernel<<<512, 256, 0, stream>>>(q_b, k_b, kr, vT, o_bf);

  gemm_bt<0><<<dim3(16, 32), 256, 0, stream>>>(o_bf, w_o, out, bo, 2048, 2048,
                                               nullptr, nullptr, nullptr);
}

// Round 14
// 355.150 us; speedup vs baseline: 1.1109x; 1.1109x over previous
//
#include <hip/hip_runtime.h>
#include <hip/hip_bf16.h>
#include <stdint.h>

// ---------------------------------------------------------------------------
// MLA forward on MI355X. Round 14:
//  - attn: r12 exact structure; Ks stride 196 -> 198 (odd-dword stride kills
//    the 4-way QK read conflict that is ~19% of attn cycles).
//  - gemm: BK=64 (halves barrier/drain count on the 2-phase critical path) +
//    st-swizzled LDS via pre-swizzled gld16 source (kills the 8-way read
//    conflict of the BK=32 64B-row layout). Epilogues unchanged.
// ---------------------------------------------------------------------------

typedef short bf16x8 __attribute__((ext_vector_type(8)));
typedef float f32x4  __attribute__((ext_vector_type(4)));
typedef unsigned int u32;

#define RMS_EPS 1.1920929e-07f
// (1/sqrt(192)) * log2(e)
#define SCALE_L2E 0.10411931095f

__device__ __forceinline__ unsigned short f2b(float f) {
  union { float f; uint32_t u; } c; c.f = f;
  uint32_t u = c.u;
  return (unsigned short)((u + 0x7FFFu + ((u >> 16) & 1u)) >> 16);
}
__device__ __forceinline__ float b2f(short s) {
  union { uint32_t u; float f; } c; c.u = ((uint32_t)(unsigned short)s) << 16;
  return c.f;
}
__device__ __forceinline__ u32 pk2(float a, float b) {
  union { __hip_bfloat162 h; u32 u; } cv;
  cv.h = __float22bfloat162_rn(float2{a, b});
  return cv.u;
}
__device__ __forceinline__ void gld16(const short* g, short* l) {
  __builtin_amdgcn_global_load_lds(
      (const __attribute__((address_space(1))) u32*)g,
      (__attribute__((address_space(3))) u32*)l, 16, 0, 0);
}

__device__ __forceinline__ void cvt4(const float* __restrict__ in,
                                     short* __restrict__ out, int i) {
  float4 v = ((const float4*)in)[i];
  union { ushort4 s; uint2 u; } o;
  o.s.x = f2b(v.x); o.s.y = f2b(v.y); o.s.z = f2b(v.z); o.s.w = f2b(v.w);
  ((uint2*)out)[i] = o.u;
}

// ---------------- merged fp32 -> bf16 conversion (all segments) --------------
__global__ void f2bf_all_kernel(
    const float* __restrict__ x,    short* __restrict__ x_bf,
    const float* __restrict__ Wqd,  short* __restrict__ w_qd,
    const float* __restrict__ Wqu,  short* __restrict__ w_qu,
    const float* __restrict__ Wkvu, short* __restrict__ w_kvu,
    const float* __restrict__ Wo,   short* __restrict__ w_o,
    const float* __restrict__ Wkvd, short* __restrict__ w_kvd) {
  int i = blockIdx.x * 256 + threadIdx.x;
  if (i < 2097152) { cvt4(x, x_bf, i); return; }
  i -= 2097152;
  if (i < 786432) { cvt4(Wqd, w_qd, i); return; }
  i -= 786432;
  if (i < 1179648) { cvt4(Wqu, w_qu, i); return; }
  i -= 1179648;
  if (i < 524288) { cvt4(Wkvu, w_kvu, i); return; }
  i -= 524288;
  if (i < 1048576) { cvt4(Wo, w_o, i); return; }
  i -= 1048576;
  if (i >= 327680) return;
  int row = i >> 9;  // 512 f4 per row
  ushort4 s = {0, 0, 0, 0};
  if (row < 576) {
    float4 v = ((const float4*)Wkvd)[i];
    s.x = f2b(v.x); s.y = f2b(v.y); s.z = f2b(v.z); s.w = f2b(v.w);
  }
  union { ushort4 ss; uint2 u; } o; o.ss = s;
  ((uint2*)w_kvd)[i] = o.u;
}

// ---------------- GEMM body: BK=64, st-swizzled LDS --------------------------
// LDS layout: element (row, granule g [8 shorts]) lives at short-offset
// row*64 + ((g ^ (row&7)) * 8). Staged by gld16 with linear dest + per-lane
// pre-swizzled global source (lane l, chunk blk: row=blk*8+(l>>3),
// g=(l&7)^(l>>3)). EPI 0/1/2 compute C^T (mfma(b,a)); EPI 3 original.
template <int EPI>
__device__ __forceinline__ void gemm_body(
    short* As, short* Bs, int row0, int col0,
    const short* __restrict__ A, const short* __restrict__ Bt,
    void* __restrict__ Cv, const float* __restrict__ bias,
    int K, int ldc,
    const float* __restrict__ fc, const float* __restrict__ fs,
    short* __restrict__ aux) {
  int t = threadIdx.x, lane = t & 63, w = t >> 6;
  int wm = w >> 1, wn = w & 1;
  int l15 = lane & 15, l4 = lane >> 4;
  f32x4 acc[4][4] = {};

  int srow = lane >> 3;                    // 0..7
  int scol = ((lane & 7) ^ srow) * 8;      // pre-swizzled source granule
  const short* Ag = A + (size_t)(row0 + srow) * K + scol;
  const short* Bg = Bt + (size_t)(col0 + srow) * K + scol;
  int xorr = (l15 & 7) << 3;               // read-side XOR (shorts)

  for (int kt = 0; kt < K; kt += 64) {
#pragma unroll
    for (int c = 0; c < 4; ++c) {
      int blk = w * 4 + c;                 // 0..15, wave-uniform
      gld16(Ag + (size_t)(blk * 8) * K + kt, As + blk * 512);
      gld16(Bg + (size_t)(blk * 8) * K + kt, Bs + blk * 512);
    }
    __syncthreads();
#pragma unroll
    for (int kk = 0; kk < 2; ++kk) {
      bf16x8 af[4], bfr[4];
#pragma unroll
      for (int i = 0; i < 4; ++i) {
        int colo = (kk * 32 + l4 * 8) ^ xorr;
        af[i]  = *(const bf16x8*)(As + (wm * 64 + i * 16 + l15) * 64 + colo);
        bfr[i] = *(const bf16x8*)(Bs + (wn * 64 + i * 16 + l15) * 64 + colo);
      }
#pragma unroll
      for (int i = 0; i < 4; ++i)
#pragma unroll
        for (int j = 0; j < 4; ++j) {
          if constexpr (EPI == 3)
            acc[i][j] = __builtin_amdgcn_mfma_f32_16x16x32_bf16(af[i], bfr[j], acc[i][j], 0, 0, 0);
          else
            acc[i][j] = __builtin_amdgcn_mfma_f32_16x16x32_bf16(bfr[j], af[i], acc[i][j], 0, 0, 0);
        }
    }
    __syncthreads();
  }

  if constexpr (EPI == 0) {
    float* C = (float*)Cv;
#pragma unroll
    for (int i = 0; i < 4; ++i) {
      int row = row0 + wm * 64 + i * 16 + l15;
#pragma unroll
      for (int j = 0; j < 4; ++j) {
        int coln = col0 + wn * 64 + j * 16 + l4 * 4;
        float4 bv = {0.f, 0.f, 0.f, 0.f};
        if (bias) bv = *(const float4*)(bias + coln);
        float4 o;
        o.x = acc[i][j][0] + bv.x; o.y = acc[i][j][1] + bv.y;
        o.z = acc[i][j][2] + bv.z; o.w = acc[i][j][3] + bv.w;
        *(float4*)(C + (size_t)row * ldc + coln) = o;
      }
    }
  } else if constexpr (EPI == 1) {
    short* C = (short*)Cv;
#pragma unroll
    for (int i = 0; i < 4; ++i) {
      int row = row0 + wm * 64 + i * 16 + l15;
#pragma unroll
      for (int j = 0; j < 4; ++j) {
        int coln = col0 + wn * 64 + j * 16 + l4 * 4;
        uint2 o;
        o.x = pk2(acc[i][j][0], acc[i][j][1]);
        o.y = pk2(acc[i][j][2], acc[i][j][3]);
        *(uint2*)(C + (size_t)row * ldc + coln) = o;
      }
    }
  } else if constexpr (EPI == 2) {
    short* qb = (short*)Cv;
#pragma unroll
    for (int i = 0; i < 4; ++i) {
      int row = row0 + wm * 64 + i * 16 + l15;
      int b = row >> 11, s = row & 2047;
#pragma unroll
      for (int j = 0; j < 4; ++j) {
        int coln = col0 + wn * 64 + j * 16 + l4 * 4;
        int h = coln / 192;
        int d0 = coln - h * 192;
        float v0 = acc[i][j][0], v1 = acc[i][j][1];
        float v2 = acc[i][j][2], v3 = acc[i][j][3];
        float o0, o1, o2, o3;
        if (d0 >= 128) {
          int ir0 = (d0 - 128) >> 1;
          float c0 = fc[s * 32 + ir0], s0 = fs[s * 32 + ir0];
          float c1 = fc[s * 32 + ir0 + 1], s1 = fs[s * 32 + ir0 + 1];
          o0 = v0 * c0 - v1 * s0; o1 = v0 * s0 + v1 * c0;
          o2 = v2 * c1 - v3 * s1; o3 = v2 * s1 + v3 * c1;
        } else {
          o0 = v0; o1 = v1; o2 = v2; o3 = v3;
        }
        uint2 o;
        o.x = pk2(o0 * SCALE_L2E, o1 * SCALE_L2E);
        o.y = pk2(o2 * SCALE_L2E, o3 * SCALE_L2E);
        *(uint2*)(qb + ((size_t)((b * 16 + h) * 2048 + s)) * 192 + d0) = o;
      }
    }
  } else {  // EPI == 3
    short* kb = (short*)Cv;
    short* vT = aux;
    int h = col0 >> 8;
    if ((col0 & 128) == 0) {
#pragma unroll
      for (int j = 0; j < 4; ++j) {
        int d = wn * 64 + j * 16 + l15;
#pragma unroll
        for (int i = 0; i < 4; ++i) {
          int rowb = row0 + wm * 64 + i * 16 + l4 * 4;
#pragma unroll
          for (int r = 0; r < 4; ++r) {
            int row = rowb + r;
            int b = row >> 11, s = row & 2047;
            kb[((size_t)((b * 16 + h) * 2048 + s)) * 128 + d] = (short)f2b(acc[i][j][r]);
          }
        }
      }
    } else {
#pragma unroll
      for (int j = 0; j < 4; ++j) {
        int dv = wn * 64 + j * 16 + l15;
#pragma unroll
        for (int i = 0; i < 4; ++i) {
          int s0 = row0 + wm * 64 + i * 16 + l4 * 4;
          int b = s0 >> 11, s = s0 & 2047;
          short4 o;
          o.x = (short)f2b(acc[i][j][0]);
          o.y = (short)f2b(acc[i][j][1]);
          o.z = (short)f2b(acc[i][j][2]);
          o.w = (short)f2b(acc[i][j][3]);
          *(short4*)(vT + ((size_t)((b * 16 + h) * 128 + dv)) * 2048 + s) = o;
        }
      }
    }
  }
}

template <int EPI>
__global__ __launch_bounds__(256) void gemm_bt(
    const short* __restrict__ A, const short* __restrict__ Bt,
    void* __restrict__ Cv, const float* __restrict__ bias,
    int K, int ldc,
    const float* __restrict__ fc, const float* __restrict__ fs,
    short* __restrict__ aux) {
  __shared__ __align__(16) short As[128 * 64];
  __shared__ __align__(16) short Bs[128 * 64];
  int nx = gridDim.x;
  int lin = blockIdx.y * nx + blockIdx.x;
  int cpx = (nx * gridDim.y) >> 3;
  int swz = (lin & 7) * cpx + (lin >> 3);
  int row0 = (swz / nx) * 128, col0 = (swz % nx) * 128;
  gemm_body<EPI>(As, Bs, row0, col0, A, Bt, Cv, bias, K, ldc, fc, fs, aux);
}

// merged up-projections: blocks [0,768) = G2 (q rope), [768,1792) = G4 (kv).
__global__ __launch_bounds__(256) void gemm_up(
    const short* __restrict__ qn, const short* __restrict__ wqu,
    short* __restrict__ q_b,
    const short* __restrict__ ckvn, const short* __restrict__ wkvu,
    short* __restrict__ k_b, short* __restrict__ vT,
    const float* __restrict__ fc, const float* __restrict__ fs) {
  __shared__ __align__(16) short As[128 * 64];
  __shared__ __align__(16) short Bs[128 * 64];
  int bb = blockIdx.x;
  if (bb < 768) {
    int cpx = 768 >> 3;
    int swz = (bb & 7) * cpx + (bb >> 3);
    int row0 = (swz / 24) * 128, col0 = (swz % 24) * 128;
    gemm_body<2>(As, Bs, row0, col0, qn, wqu, q_b, nullptr, 1536, 0, fc, fs, nullptr);
  } else {
    int bb2 = bb - 768;
    int cpx = 1024 >> 3;
    int swz = (bb2 & 7) * cpx + (bb2 >> 3);
    int row0 = (swz / 32) * 128, col0 = (swz % 32) * 128;
    gemm_body<3>(As, Bs, row0, col0, ckvn, wkvu, k_b, nullptr, 512, 0, nullptr, nullptr, vT);
  }
}

// ---------------- merged rmsnorm(q) + rmsnorm(kv) + krope --------------------
template <int W>
__device__ __forceinline__ void rms_body(
    const short* __restrict__ in, const float* __restrict__ wgt,
    short* __restrict__ out, int ld_in, int blk) {
  constexpr int NC = W / 512;
  int row = blk * 4 + (threadIdx.x >> 6);
  int lane = threadIdx.x & 63;
  const short* x = in + (size_t)row * ld_in + lane * 8;
  float vals[NC * 8];
  float ss = 0.f;
#pragma unroll
  for (int c = 0; c < NC; ++c) {
    bf16x8 v = *(const bf16x8*)(x + c * 512);
#pragma unroll
    for (int k = 0; k < 8; ++k) {
      float f = b2f(v[k]);
      vals[c * 8 + k] = f; ss += f * f;
    }
  }
#pragma unroll
  for (int off = 32; off > 0; off >>= 1) ss += __shfl_xor(ss, off);
  float rs = rsqrtf(ss / (float)W + RMS_EPS);
  short* o = out + (size_t)row * W + lane * 8;
#pragma unroll
  for (int c = 0; c < NC; ++c) {
    const float4* wp = (const float4*)(wgt + c * 512 + lane * 8);
    float4 w0 = wp[0], w1 = wp[1];
    ushort4 lo, hi;
    lo.x = f2b(vals[c * 8 + 0] * rs * w0.x);
    lo.y = f2b(vals[c * 8 + 1] * rs * w0.y);
    lo.z = f2b(vals[c * 8 + 2] * rs * w0.z);
    lo.w = f2b(vals[c * 8 + 3] * rs * w0.w);
    hi.x = f2b(vals[c * 8 + 4] * rs * w1.x);
    hi.y = f2b(vals[c * 8 + 5] * rs * w1.y);
    hi.z = f2b(vals[c * 8 + 6] * rs * w1.z);
    hi.w = f2b(vals[c * 8 + 7] * rs * w1.w);
    *(ushort4*)(o + c * 512) = lo;
    *(ushort4*)(o + c * 512 + 4) = hi;
  }
}

__global__ __launch_bounds__(256) void norm_krope_kernel(
    const short* __restrict__ c1,
    const float* __restrict__ qnw, short* __restrict__ qn,
    const float* __restrict__ kvnw, short* __restrict__ ckvn,
    const float* __restrict__ fc, const float* __restrict__ fs,
    short* __restrict__ kr) {
  int bb = blockIdx.x;
  if (bb < 1024) {
    rms_body<1536>(c1, qnw, qn, 2176, bb);
  } else if (bb < 2048) {
    rms_body<512>(c1 + 1600, kvnw, ckvn, 2176, bb - 1024);
  } else {
    int idx = (bb - 2048) * 256 + threadIdx.x;  // B*S*32 = 131072
    int i = idx & 31;
    int s = (idx >> 5) & 2047;
    int b = idx >> 16;
    const short* row = c1 + (size_t)(b * 2048 + s) * 2176 + 1536 + 2 * i;
    float x0 = b2f(row[0]), x1 = b2f(row[1]);
    float c = fc[s * 32 + i], sn = fs[s * 32 + i];
    uint32_t pk = (uint32_t)f2b(x0 * c - x1 * sn) | ((uint32_t)f2b(x0 * sn + x1 * c) << 16);
    *(uint32_t*)(kr + ((size_t)(b * 2048 + s)) * 64 + 2 * i) = pk;
  }
}

// ---------------- flash attention (r12 + odd-stride Ks) ----------------------
// grid 512; XCD remap, paired q-tiles {qx, 31-qx} => uniform 33 iters/block.
// Ks stride 198 shorts (99 dwords, odd) => QK frag reads ~2 lanes/bank (free).
__global__ __launch_bounds__(256, 2) void attn_kernel(
    const short* __restrict__ qb, const short* __restrict__ kb,
    const short* __restrict__ kr, const short* __restrict__ vtb,
    short* __restrict__ ob) {
  __shared__ __align__(16) short Ks[64 * 198];
  __shared__ __align__(16) short Vs[128 * 70];
  int bid = blockIdx.x;
  int xcd = bid & 7, kk2 = bid >> 3;       // kk2: 0..63
  int bh = xcd * 4 + (kk2 >> 4);           // 4 bh per XCD
  int qx = kk2 & 15;
  int b = bh >> 4, h = bh & 15;
  int t = threadIdx.x, lane = t & 63, w = t >> 6;
  int l15 = lane & 15, l4 = lane >> 4;
  const short* Kbh = kb + (size_t)bh * 2048 * 128;
  const short* krb = kr + (size_t)b * 2048 * 64;
  const short* Vbh = vtb + (size_t)bh * 128 * 2048;

  // non-divergent staging geometry
  int kn_r = t >> 4, kn_c = (t & 15) * 8;          // nope: 4 chunks of 16 rows
  int kr_r = t >> 3, kr_c = (t & 7) * 8;           // rope: 2 chunks of 32 rows
  int v_d = t >> 3, v_c = (t & 7) * 8;             // V: 4 chunks of 32 d-rows

  // bpermute source lanes for P redistribution (byte addr = lane*4)
  int sA = (l15 + ((l4 & 1) << 5)) << 2;
  int sB = sA + (16 << 2);
  bool chi = (l4 >> 1) != 0;

  for (int half = 0; half < 2; ++half) {
    int qt = half ? (31 - qx) : qx;
    int q0 = qt * 64;
    const short* Qbase = qb + ((size_t)bh * 2048 + q0 + w * 16) * 192;
    bf16x8 qf[6];
#pragma unroll
    for (int kk = 0; kk < 6; ++kk)
      qf[kk] = *(const bf16x8*)(Qbase + (size_t)l15 * 192 + kk * 32 + l4 * 8);
    f32x4 oaccT[8] = {};
    float m_i = -1e30f, l_i = 0.f;
    int qcol = q0 + w * 16 + l15;
    int kend = q0 + 64;

    // prefetch tile 0 into registers
    bf16x8 pn0, pn1, pn2, pn3, pr0, pr1, pv0, pv1, pv2, pv3;
    pn0 = *(const bf16x8*)(Kbh + (size_t)(kn_r) * 128 + kn_c);
    pn1 = *(const bf16x8*)(Kbh + (size_t)(kn_r + 16) * 128 + kn_c);
    pn2 = *(const bf16x8*)(Kbh + (size_t)(kn_r + 32) * 128 + kn_c);
    pn3 = *(const bf16x8*)(Kbh + (size_t)(kn_r + 48) * 128 + kn_c);
    pr0 = *(const bf16x8*)(krb + (size_t)(kr_r) * 64 + kr_c);
    pr1 = *(const bf16x8*)(krb + (size_t)(kr_r + 32) * 64 + kr_c);
    pv0 = *(const bf16x8*)(Vbh + (size_t)(v_d) * 2048 + v_c);
    pv1 = *(const bf16x8*)(Vbh + (size_t)(v_d + 32) * 2048 + v_c);
    pv2 = *(const bf16x8*)(Vbh + (size_t)(v_d + 64) * 2048 + v_c);
    pv3 = *(const bf16x8*)(Vbh + (size_t)(v_d + 96) * 2048 + v_c);

    for (int kt = 0; kt < kend; kt += 64) {
      // write prefetched tile to LDS
      *(bf16x8*)(Ks + (kn_r) * 198 + kn_c) = pn0;
      *(bf16x8*)(Ks + (kn_r + 16) * 198 + kn_c) = pn1;
      *(bf16x8*)(Ks + (kn_r + 32) * 198 + kn_c) = pn2;
      *(bf16x8*)(Ks + (kn_r + 48) * 198 + kn_c) = pn3;
      *(bf16x8*)(Ks + (kr_r) * 198 + 128 + kr_c) = pr0;
      *(bf16x8*)(Ks + (kr_r + 32) * 198 + 128 + kr_c) = pr1;
      *(bf16x8*)(Vs + (v_d) * 70 + v_c) = pv0;
      *(bf16x8*)(Vs + (v_d + 32) * 70 + v_c) = pv1;
      *(bf16x8*)(Vs + (v_d + 64) * 70 + v_c) = pv2;
      *(bf16x8*)(Vs + (v_d + 96) * 70 + v_c) = pv3;
      __syncthreads();
      // issue NEXT tile's loads — fly under this tile's compute.
      if (kt + 64 < kend) {
        int k2 = kt + 64;
        pn0 = *(const bf16x8*)(Kbh + (size_t)(k2 + kn_r) * 128 + kn_c);
        pn1 = *(const bf16x8*)(Kbh + (size_t)(k2 + kn_r + 16) * 128 + kn_c);
        pn2 = *(const bf16x8*)(Kbh + (size_t)(k2 + kn_r + 32) * 128 + kn_c);
        pn3 = *(const bf16x8*)(Kbh + (size_t)(k2 + kn_r + 48) * 128 + kn_c);
        pr0 = *(const bf16x8*)(krb + (size_t)(k2 + kr_r) * 64 + kr_c);
        pr1 = *(const bf16x8*)(krb + (size_t)(k2 + kr_r + 32) * 64 + kr_c);
        pv0 = *(const bf16x8*)(Vbh + (size_t)(v_d) * 2048 + k2 + v_c);
        pv1 = *(const bf16x8*)(Vbh + (size_t)(v_d + 32) * 2048 + k2 + v_c);
        pv2 = *(const bf16x8*)(Vbh + (size_t)(v_d + 64) * 2048 + k2 + v_c);
        pv3 = *(const bf16x8*)(Vbh + (size_t)(v_d + 96) * 2048 + k2 + v_c);
      }

      // S^T: A = K rows, B = Q cols
      f32x4 s[4] = {};
      __builtin_amdgcn_s_setprio(1);
#pragma unroll
      for (int kk = 0; kk < 6; ++kk) {
#pragma unroll
        for (int c = 0; c < 4; ++c) {
          bf16x8 kf = *(const bf16x8*)(Ks + (c * 16 + l15) * 198 + kk * 32 + l4 * 8);
          s[c] = __builtin_amdgcn_mfma_f32_16x16x32_bf16(kf, qf[kk], s[c], 0, 0, 0);
        }
      }
      __builtin_amdgcn_s_setprio(0);

      if (kt == q0) {  // diagonal tile: mask k > q
#pragma unroll
        for (int c = 0; c < 4; ++c)
#pragma unroll
          for (int r = 0; r < 4; ++r) {
            int k = kt + c * 16 + l4 * 4 + r;
            if (k > qcol) s[c][r] = -1e30f;
          }
      }
      // per-q softmax: in-lane over 16 + cross-group (xor 16, 32)
      float mx = fmaxf(fmaxf(fmaxf(s[0][0], s[0][1]), fmaxf(s[0][2], s[0][3])),
                       fmaxf(fmaxf(s[1][0], s[1][1]), fmaxf(s[1][2], s[1][3])));
      mx = fmaxf(mx, fmaxf(fmaxf(fmaxf(s[2][0], s[2][1]), fmaxf(s[2][2], s[2][3])),
                           fmaxf(fmaxf(s[3][0], s[3][1]), fmaxf(s[3][2], s[3][3]))));
      mx = fmaxf(mx, __shfl_xor(mx, 16));
      mx = fmaxf(mx, __shfl_xor(mx, 32));
      float newm = fmaxf(m_i, mx);
      float alpha = __builtin_amdgcn_exp2f(m_i - newm);
      float rs = 0.f;
#pragma unroll
      for (int c = 0; c < 4; ++c)
#pragma unroll
        for (int r = 0; r < 4; ++r) {
          float p = __builtin_amdgcn_exp2f(s[c][r] - newm);
          s[c][r] = p; rs += p;
        }
      rs += __shfl_xor(rs, 16);
      rs += __shfl_xor(rs, 32);
      l_i = l_i * alpha + rs;
      m_i = newm;
#pragma unroll
      for (int dt = 0; dt < 8; ++dt)
#pragma unroll
        for (int r = 0; r < 4; ++r) oaccT[dt][r] *= alpha;

      // pack P^T to bf16 pairs (named regs; no runtime indexing)
      u32 pk00 = pk2(s[0][0], s[0][1]), pk01 = pk2(s[0][2], s[0][3]);
      u32 pk10 = pk2(s[1][0], s[1][1]), pk11 = pk2(s[1][2], s[1][3]);
      u32 pk20 = pk2(s[2][0], s[2][1]), pk21 = pk2(s[2][2], s[2][3]);
      u32 pk30 = pk2(s[3][0], s[3][1]), pk31 = pk2(s[3][2], s[3][3]);
      union { bf16x8 v; u32 u[4]; } P0, P1;
      {
        u32 a0 = __builtin_amdgcn_ds_bpermute(sA, (int)pk00);
        u32 a1 = __builtin_amdgcn_ds_bpermute(sA, (int)pk01);
        u32 a2 = __builtin_amdgcn_ds_bpermute(sB, (int)pk00);
        u32 a3 = __builtin_amdgcn_ds_bpermute(sB, (int)pk01);
        u32 b0 = __builtin_amdgcn_ds_bpermute(sA, (int)pk10);
        u32 b1 = __builtin_amdgcn_ds_bpermute(sA, (int)pk11);
        u32 b2 = __builtin_amdgcn_ds_bpermute(sB, (int)pk10);
        u32 b3 = __builtin_amdgcn_ds_bpermute(sB, (int)pk11);
        P0.u[0] = chi ? b0 : a0; P0.u[1] = chi ? b1 : a1;
        P0.u[2] = chi ? b2 : a2; P0.u[3] = chi ? b3 : a3;
      }
      {
        u32 a0 = __builtin_amdgcn_ds_bpermute(sA, (int)pk20);
        u32 a1 = __builtin_amdgcn_ds_bpermute(sA, (int)pk21);
        u32 a2 = __builtin_amdgcn_ds_bpermute(sB, (int)pk20);
        u32 a3 = __builtin_amdgcn_ds_bpermute(sB, (int)pk21);
        u32 b0 = __builtin_amdgcn_ds_bpermute(sA, (int)pk30);
        u32 b1 = __builtin_amdgcn_ds_bpermute(sA, (int)pk31);
        u32 b2 = __builtin_amdgcn_ds_bpermute(sB, (int)pk30);
        u32 b3 = __builtin_amdgcn_ds_bpermute(sB, (int)pk31);
        P1.u[0] = chi ? b0 : a0; P1.u[1] = chi ? b1 : a1;
        P1.u[2] = chi ? b2 : a2; P1.u[3] = chi ? b3 : a3;
      }

      // O^T += V^T-frag x P^T-frag
      __builtin_amdgcn_s_setprio(1);
#pragma unroll
      for (int dt = 0; dt < 8; ++dt) {
        bf16x8 vf0 = *(const bf16x8*)(Vs + (dt * 16 + l15) * 70 + l4 * 8);
        bf16x8 vf1 = *(const bf16x8*)(Vs + (dt * 16 + l15) * 70 + 32 + l4 * 8);
        oaccT[dt] = __builtin_amdgcn_mfma_f32_16x16x32_bf16(vf0, P0.v, oaccT[dt], 0, 0, 0);
        oaccT[dt] = __builtin_amdgcn_mfma_f32_16x16x32_bf16(vf1, P1.v, oaccT[dt], 0, 0, 0);
      }
      __builtin_amdgcn_s_setprio(0);
      __syncthreads();
    }
    // epilogue: lane holds O^T[d = dt*16 + l4*4 + r][q = qcol]
    float inv = 1.0f / l_i;
    short* dst = ob + ((size_t)(b * 2048 + qcol)) * 2048 + h * 128;
#pragma unroll
    for (int dt = 0; dt < 8; ++dt) {
      uint2 o;
      o.x = pk2(oaccT[dt][0] * inv, oaccT[dt][1] * inv);
      o.y = pk2(oaccT[dt][2] * inv, oaccT[dt][3] * inv);
      *(uint2*)(dst + dt * 16 + l4 * 4) = o;
    }
  }
}

// ---------------------------------------------------------------------------
extern "C" void kernel_launch(void* const* d_in, const int* in_sizes, int n_in,
                              void* d_out, int out_size, void* d_ws, size_t ws_size,
                              hipStream_t stream) {
  const float* x    = (const float*)d_in[0];
  const float* fcos = (const float*)d_in[1];
  const float* fsin = (const float*)d_in[2];
  const float* Wqd  = (const float*)d_in[3];
  const float* qnw  = (const float*)d_in[4];
  const float* Wqu  = (const float*)d_in[5];
  const float* Wkvd = (const float*)d_in[6];
  const float* kvnw = (const float*)d_in[7];
  const float* Wkvu = (const float*)d_in[8];
  const float* Wo   = (const float*)d_in[9];
  const float* bo   = (const float*)d_in[10];
  float* out = (float*)d_out;
  char* ws = (char*)d_ws;

  short* x_bf  = (short*)(ws + 0);           // 4096x2048 bf16
  short* w_cat = (short*)(ws + 16777216);    // 2176x2048 (Wqd;Wkvd pad)
  short* w_qu  = (short*)(ws + 25690112);    // 3072x1536
  short* w_kvu = (short*)(ws + 35127296);    // 4096x512
  short* w_o   = (short*)(ws + 39321600);    // 2048x2048
  short* c1    = (short*)(ws + 47710208);    // 4096x2176 bf16 (qdown|krope|ckv)
  short* qn    = (short*)(ws + 65536000);    // 4096x1536 bf16
  short* ckvn  = (short*)(ws + 78118912);    // 4096x512 bf16
  short* q_b   = (short*)(ws + 82313216);    // (B,H,S,192) bf16
  short* k_b   = (short*)(ws + 107479040);   // (B,H,S,128) bf16 (nope only)
  short* vT    = (short*)(ws + 132644864);   // (B,H,128,S) bf16
  short* o_bf  = (short*)(ws + 149422080);   // (B,S,2048) bf16
  short* kr    = (short*)(ws + 166199296);   // (B,S,64) bf16 roped shared k

  f2bf_all_kernel<<<23296, 256, 0, stream>>>(x, x_bf, Wqd, w_cat, Wqu, w_qu,
                                             Wkvu, w_kvu, Wo, w_o,
                                             Wkvd, w_cat + 1536 * 2048);

  gemm_bt<1><<<dim3(17, 32), 256, 0, stream>>>(x_bf, w_cat, c1, nullptr, 2048, 2176,
                                               nullptr, nullptr, nullptr);
  norm_krope_kernel<<<2560, 256, 0, stream>>>(c1, qnw, qn, kvnw, ckvn,
                                              fcos, fsin, kr);

  gemm_up<<<1792, 256, 0, stream>>>(qn, w_qu, q_b, ckvn, w_kvu, k_b, vT,
                                    fcos, fsin);

  attn_kernel<<<512, 256, 0, stream>>>(q_b, k_b, kr, vT, o_bf);

  gemm_bt<0><<<dim3(16, 32), 256, 0, stream>>>(o_bf, w_o, out, bo, 2048, 2048,
                                               nullptr, nullptr, nullptr);
}

// Round 15
// 335.595 us; speedup vs baseline: 1.1757x; 1.0583x over previous
//
#include <hip/hip_runtime.h>
#include <hip/hip_bf16.h>
#include <stdint.h>

// ---------------------------------------------------------------------------
// MLA forward on MI355X. Round 15 (recombination of measured-best halves):
//  - gemm: r14 BK=64 + st-swizzled LDS (verified -16us on non-attn time).
//  - attn: r12 exact (stride 196, Vs 70 — known-best 112us).
// ---------------------------------------------------------------------------

typedef short bf16x8 __attribute__((ext_vector_type(8)));
typedef float f32x4  __attribute__((ext_vector_type(4)));
typedef unsigned int u32;

#define RMS_EPS 1.1920929e-07f
// (1/sqrt(192)) * log2(e)
#define SCALE_L2E 0.10411931095f

__device__ __forceinline__ unsigned short f2b(float f) {
  union { float f; uint32_t u; } c; c.f = f;
  uint32_t u = c.u;
  return (unsigned short)((u + 0x7FFFu + ((u >> 16) & 1u)) >> 16);
}
__device__ __forceinline__ float b2f(short s) {
  union { uint32_t u; float f; } c; c.u = ((uint32_t)(unsigned short)s) << 16;
  return c.f;
}
__device__ __forceinline__ u32 pk2(float a, float b) {
  union { __hip_bfloat162 h; u32 u; } cv;
  cv.h = __float22bfloat162_rn(float2{a, b});
  return cv.u;
}
__device__ __forceinline__ void gld16(const short* g, short* l) {
  __builtin_amdgcn_global_load_lds(
      (const __attribute__((address_space(1))) u32*)g,
      (__attribute__((address_space(3))) u32*)l, 16, 0, 0);
}

__device__ __forceinline__ void cvt4(const float* __restrict__ in,
                                     short* __restrict__ out, int i) {
  float4 v = ((const float4*)in)[i];
  union { ushort4 s; uint2 u; } o;
  o.s.x = f2b(v.x); o.s.y = f2b(v.y); o.s.z = f2b(v.z); o.s.w = f2b(v.w);
  ((uint2*)out)[i] = o.u;
}

// ---------------- merged fp32 -> bf16 conversion (all segments) --------------
__global__ void f2bf_all_kernel(
    const float* __restrict__ x,    short* __restrict__ x_bf,
    const float* __restrict__ Wqd,  short* __restrict__ w_qd,
    const float* __restrict__ Wqu,  short* __restrict__ w_qu,
    const float* __restrict__ Wkvu, short* __restrict__ w_kvu,
    const float* __restrict__ Wo,   short* __restrict__ w_o,
    const float* __restrict__ Wkvd, short* __restrict__ w_kvd) {
  int i = blockIdx.x * 256 + threadIdx.x;
  if (i < 2097152) { cvt4(x, x_bf, i); return; }
  i -= 2097152;
  if (i < 786432) { cvt4(Wqd, w_qd, i); return; }
  i -= 786432;
  if (i < 1179648) { cvt4(Wqu, w_qu, i); return; }
  i -= 1179648;
  if (i < 524288) { cvt4(Wkvu, w_kvu, i); return; }
  i -= 524288;
  if (i < 1048576) { cvt4(Wo, w_o, i); return; }
  i -= 1048576;
  if (i >= 327680) return;
  int row = i >> 9;  // 512 f4 per row
  ushort4 s = {0, 0, 0, 0};
  if (row < 576) {
    float4 v = ((const float4*)Wkvd)[i];
    s.x = f2b(v.x); s.y = f2b(v.y); s.z = f2b(v.z); s.w = f2b(v.w);
  }
  union { ushort4 ss; uint2 u; } o; o.ss = s;
  ((uint2*)w_kvd)[i] = o.u;
}

// ---------------- GEMM body: BK=64, st-swizzled LDS (r14, verified) ----------
// LDS: element (row, granule g) at row*64 + ((g ^ (row&7)) * 8). Staged by
// gld16 linear dest + pre-swizzled per-lane global source. EPI 0/1/2 = C^T.
template <int EPI>
__device__ __forceinline__ void gemm_body(
    short* As, short* Bs, int row0, int col0,
    const short* __restrict__ A, const short* __restrict__ Bt,
    void* __restrict__ Cv, const float* __restrict__ bias,
    int K, int ldc,
    const float* __restrict__ fc, const float* __restrict__ fs,
    short* __restrict__ aux) {
  int t = threadIdx.x, lane = t & 63, w = t >> 6;
  int wm = w >> 1, wn = w & 1;
  int l15 = lane & 15, l4 = lane >> 4;
  f32x4 acc[4][4] = {};

  int srow = lane >> 3;                    // 0..7
  int scol = ((lane & 7) ^ srow) * 8;      // pre-swizzled source granule
  const short* Ag = A + (size_t)(row0 + srow) * K + scol;
  const short* Bg = Bt + (size_t)(col0 + srow) * K + scol;
  int xorr = (l15 & 7) << 3;               // read-side XOR (shorts)

  for (int kt = 0; kt < K; kt += 64) {
#pragma unroll
    for (int c = 0; c < 4; ++c) {
      int blk = w * 4 + c;                 // 0..15, wave-uniform
      gld16(Ag + (size_t)(blk * 8) * K + kt, As + blk * 512);
      gld16(Bg + (size_t)(blk * 8) * K + kt, Bs + blk * 512);
    }
    __syncthreads();
#pragma unroll
    for (int kk = 0; kk < 2; ++kk) {
      bf16x8 af[4], bfr[4];
#pragma unroll
      for (int i = 0; i < 4; ++i) {
        int colo = (kk * 32 + l4 * 8) ^ xorr;
        af[i]  = *(const bf16x8*)(As + (wm * 64 + i * 16 + l15) * 64 + colo);
        bfr[i] = *(const bf16x8*)(Bs + (wn * 64 + i * 16 + l15) * 64 + colo);
      }
#pragma unroll
      for (int i = 0; i < 4; ++i)
#pragma unroll
        for (int j = 0; j < 4; ++j) {
          if constexpr (EPI == 3)
            acc[i][j] = __builtin_amdgcn_mfma_f32_16x16x32_bf16(af[i], bfr[j], acc[i][j], 0, 0, 0);
          else
            acc[i][j] = __builtin_amdgcn_mfma_f32_16x16x32_bf16(bfr[j], af[i], acc[i][j], 0, 0, 0);
        }
    }
    __syncthreads();
  }

  if constexpr (EPI == 0) {
    float* C = (float*)Cv;
#pragma unroll
    for (int i = 0; i < 4; ++i) {
      int row = row0 + wm * 64 + i * 16 + l15;
#pragma unroll
      for (int j = 0; j < 4; ++j) {
        int coln = col0 + wn * 64 + j * 16 + l4 * 4;
        float4 bv = {0.f, 0.f, 0.f, 0.f};
        if (bias) bv = *(const float4*)(bias + coln);
        float4 o;
        o.x = acc[i][j][0] + bv.x; o.y = acc[i][j][1] + bv.y;
        o.z = acc[i][j][2] + bv.z; o.w = acc[i][j][3] + bv.w;
        *(float4*)(C + (size_t)row * ldc + coln) = o;
      }
    }
  } else if constexpr (EPI == 1) {
    short* C = (short*)Cv;
#pragma unroll
    for (int i = 0; i < 4; ++i) {
      int row = row0 + wm * 64 + i * 16 + l15;
#pragma unroll
      for (int j = 0; j < 4; ++j) {
        int coln = col0 + wn * 64 + j * 16 + l4 * 4;
        uint2 o;
        o.x = pk2(acc[i][j][0], acc[i][j][1]);
        o.y = pk2(acc[i][j][2], acc[i][j][3]);
        *(uint2*)(C + (size_t)row * ldc + coln) = o;
      }
    }
  } else if constexpr (EPI == 2) {
    short* qb = (short*)Cv;
#pragma unroll
    for (int i = 0; i < 4; ++i) {
      int row = row0 + wm * 64 + i * 16 + l15;
      int b = row >> 11, s = row & 2047;
#pragma unroll
      for (int j = 0; j < 4; ++j) {
        int coln = col0 + wn * 64 + j * 16 + l4 * 4;
        int h = coln / 192;
        int d0 = coln - h * 192;
        float v0 = acc[i][j][0], v1 = acc[i][j][1];
        float v2 = acc[i][j][2], v3 = acc[i][j][3];
        float o0, o1, o2, o3;
        if (d0 >= 128) {
          int ir0 = (d0 - 128) >> 1;
          float c0 = fc[s * 32 + ir0], s0 = fs[s * 32 + ir0];
          float c1 = fc[s * 32 + ir0 + 1], s1 = fs[s * 32 + ir0 + 1];
          o0 = v0 * c0 - v1 * s0; o1 = v0 * s0 + v1 * c0;
          o2 = v2 * c1 - v3 * s1; o3 = v2 * s1 + v3 * c1;
        } else {
          o0 = v0; o1 = v1; o2 = v2; o3 = v3;
        }
        uint2 o;
        o.x = pk2(o0 * SCALE_L2E, o1 * SCALE_L2E);
        o.y = pk2(o2 * SCALE_L2E, o3 * SCALE_L2E);
        *(uint2*)(qb + ((size_t)((b * 16 + h) * 2048 + s)) * 192 + d0) = o;
      }
    }
  } else {  // EPI == 3
    short* kb = (short*)Cv;
    short* vT = aux;
    int h = col0 >> 8;
    if ((col0 & 128) == 0) {
#pragma unroll
      for (int j = 0; j < 4; ++j) {
        int d = wn * 64 + j * 16 + l15;
#pragma unroll
        for (int i = 0; i < 4; ++i) {
          int rowb = row0 + wm * 64 + i * 16 + l4 * 4;
#pragma unroll
          for (int r = 0; r < 4; ++r) {
            int row = rowb + r;
            int b = row >> 11, s = row & 2047;
            kb[((size_t)((b * 16 + h) * 2048 + s)) * 128 + d] = (short)f2b(acc[i][j][r]);
          }
        }
      }
    } else {
#pragma unroll
      for (int j = 0; j < 4; ++j) {
        int dv = wn * 64 + j * 16 + l15;
#pragma unroll
        for (int i = 0; i < 4; ++i) {
          int s0 = row0 + wm * 64 + i * 16 + l4 * 4;
          int b = s0 >> 11, s = s0 & 2047;
          short4 o;
          o.x = (short)f2b(acc[i][j][0]);
          o.y = (short)f2b(acc[i][j][1]);
          o.z = (short)f2b(acc[i][j][2]);
          o.w = (short)f2b(acc[i][j][3]);
          *(short4*)(vT + ((size_t)((b * 16 + h) * 128 + dv)) * 2048 + s) = o;
        }
      }
    }
  }
}

template <int EPI>
__global__ __launch_bounds__(256) void gemm_bt(
    const short* __restrict__ A, const short* __restrict__ Bt,
    void* __restrict__ Cv, const float* __restrict__ bias,
    int K, int ldc,
    const float* __restrict__ fc, const float* __restrict__ fs,
    short* __restrict__ aux) {
  __shared__ __align__(16) short As[128 * 64];
  __shared__ __align__(16) short Bs[128 * 64];
  int nx = gridDim.x;
  int lin = blockIdx.y * nx + blockIdx.x;
  int cpx = (nx * gridDim.y) >> 3;
  int swz = (lin & 7) * cpx + (lin >> 3);
  int row0 = (swz / nx) * 128, col0 = (swz % nx) * 128;
  gemm_body<EPI>(As, Bs, row0, col0, A, Bt, Cv, bias, K, ldc, fc, fs, aux);
}

// merged up-projections: blocks [0,768) = G2 (q rope), [768,1792) = G4 (kv).
__global__ __launch_bounds__(256) void gemm_up(
    const short* __restrict__ qn, const short* __restrict__ wqu,
    short* __restrict__ q_b,
    const short* __restrict__ ckvn, const short* __restrict__ wkvu,
    short* __restrict__ k_b, short* __restrict__ vT,
    const float* __restrict__ fc, const float* __restrict__ fs) {
  __shared__ __align__(16) short As[128 * 64];
  __shared__ __align__(16) short Bs[128 * 64];
  int bb = blockIdx.x;
  if (bb < 768) {
    int cpx = 768 >> 3;
    int swz = (bb & 7) * cpx + (bb >> 3);
    int row0 = (swz / 24) * 128, col0 = (swz % 24) * 128;
    gemm_body<2>(As, Bs, row0, col0, qn, wqu, q_b, nullptr, 1536, 0, fc, fs, nullptr);
  } else {
    int bb2 = bb - 768;
    int cpx = 1024 >> 3;
    int swz = (bb2 & 7) * cpx + (bb2 >> 3);
    int row0 = (swz / 32) * 128, col0 = (swz % 32) * 128;
    gemm_body<3>(As, Bs, row0, col0, ckvn, wkvu, k_b, nullptr, 512, 0, nullptr, nullptr, vT);
  }
}

// ---------------- merged rmsnorm(q) + rmsnorm(kv) + krope --------------------
template <int W>
__device__ __forceinline__ void rms_body(
    const short* __restrict__ in, const float* __restrict__ wgt,
    short* __restrict__ out, int ld_in, int blk) {
  constexpr int NC = W / 512;
  int row = blk * 4 + (threadIdx.x >> 6);
  int lane = threadIdx.x & 63;
  const short* x = in + (size_t)row * ld_in + lane * 8;
  float vals[NC * 8];
  float ss = 0.f;
#pragma unroll
  for (int c = 0; c < NC; ++c) {
    bf16x8 v = *(const bf16x8*)(x + c * 512);
#pragma unroll
    for (int k = 0; k < 8; ++k) {
      float f = b2f(v[k]);
      vals[c * 8 + k] = f; ss += f * f;
    }
  }
#pragma unroll
  for (int off = 32; off > 0; off >>= 1) ss += __shfl_xor(ss, off);
  float rs = rsqrtf(ss / (float)W + RMS_EPS);
  short* o = out + (size_t)row * W + lane * 8;
#pragma unroll
  for (int c = 0; c < NC; ++c) {
    const float4* wp = (const float4*)(wgt + c * 512 + lane * 8);
    float4 w0 = wp[0], w1 = wp[1];
    ushort4 lo, hi;
    lo.x = f2b(vals[c * 8 + 0] * rs * w0.x);
    lo.y = f2b(vals[c * 8 + 1] * rs * w0.y);
    lo.z = f2b(vals[c * 8 + 2] * rs * w0.z);
    lo.w = f2b(vals[c * 8 + 3] * rs * w0.w);
    hi.x = f2b(vals[c * 8 + 4] * rs * w1.x);
    hi.y = f2b(vals[c * 8 + 5] * rs * w1.y);
    hi.z = f2b(vals[c * 8 + 6] * rs * w1.z);
    hi.w = f2b(vals[c * 8 + 7] * rs * w1.w);
    *(ushort4*)(o + c * 512) = lo;
    *(ushort4*)(o + c * 512 + 4) = hi;
  }
}

__global__ __launch_bounds__(256) void norm_krope_kernel(
    const short* __restrict__ c1,
    const float* __restrict__ qnw, short* __restrict__ qn,
    const float* __restrict__ kvnw, short* __restrict__ ckvn,
    const float* __restrict__ fc, const float* __restrict__ fs,
    short* __restrict__ kr) {
  int bb = blockIdx.x;
  if (bb < 1024) {
    rms_body<1536>(c1, qnw, qn, 2176, bb);
  } else if (bb < 2048) {
    rms_body<512>(c1 + 1600, kvnw, ckvn, 2176, bb - 1024);
  } else {
    int idx = (bb - 2048) * 256 + threadIdx.x;  // B*S*32 = 131072
    int i = idx & 31;
    int s = (idx >> 5) & 2047;
    int b = idx >> 16;
    const short* row = c1 + (size_t)(b * 2048 + s) * 2176 + 1536 + 2 * i;
    float x0 = b2f(row[0]), x1 = b2f(row[1]);
    float c = fc[s * 32 + i], sn = fs[s * 32 + i];
    uint32_t pk = (uint32_t)f2b(x0 * c - x1 * sn) | ((uint32_t)f2b(x0 * sn + x1 * c) << 16);
    *(uint32_t*)(kr + ((size_t)(b * 2048 + s)) * 64 + 2 * i) = pk;
  }
}

// ---------------- flash attention (r12 exact: stride 196/70) -----------------
// grid 512; XCD remap, paired q-tiles {qx, 31-qx} => uniform 33 iters/block.
// T14: next tile's loads issue AFTER the barrier, land during compute.
__global__ __launch_bounds__(256, 2) void attn_kernel(
    const short* __restrict__ qb, const short* __restrict__ kb,
    const short* __restrict__ kr, const short* __restrict__ vtb,
    short* __restrict__ ob) {
  __shared__ __align__(16) short Ks[64 * 196];
  __shared__ __align__(16) short Vs[128 * 70];
  int bid = blockIdx.x;
  int xcd = bid & 7, kk2 = bid >> 3;       // kk2: 0..63
  int bh = xcd * 4 + (kk2 >> 4);           // 4 bh per XCD
  int qx = kk2 & 15;
  int b = bh >> 4, h = bh & 15;
  int t = threadIdx.x, lane = t & 63, w = t >> 6;
  int l15 = lane & 15, l4 = lane >> 4;
  const short* Kbh = kb + (size_t)bh * 2048 * 128;
  const short* krb = kr + (size_t)b * 2048 * 64;
  const short* Vbh = vtb + (size_t)bh * 128 * 2048;

  // non-divergent staging geometry
  int kn_r = t >> 4, kn_c = (t & 15) * 8;          // nope: 4 chunks of 16 rows
  int kr_r = t >> 3, kr_c = (t & 7) * 8;           // rope: 2 chunks of 32 rows
  int v_d = t >> 3, v_c = (t & 7) * 8;             // V: 4 chunks of 32 d-rows

  // bpermute source lanes for P redistribution (byte addr = lane*4)
  int sA = (l15 + ((l4 & 1) << 5)) << 2;
  int sB = sA + (16 << 2);
  bool chi = (l4 >> 1) != 0;

  for (int half = 0; half < 2; ++half) {
    int qt = half ? (31 - qx) : qx;
    int q0 = qt * 64;
    const short* Qbase = qb + ((size_t)bh * 2048 + q0 + w * 16) * 192;
    bf16x8 qf[6];
#pragma unroll
    for (int kk = 0; kk < 6; ++kk)
      qf[kk] = *(const bf16x8*)(Qbase + (size_t)l15 * 192 + kk * 32 + l4 * 8);
    f32x4 oaccT[8] = {};
    float m_i = -1e30f, l_i = 0.f;
    int qcol = q0 + w * 16 + l15;
    int kend = q0 + 64;

    // prefetch tile 0 into registers
    bf16x8 pn0, pn1, pn2, pn3, pr0, pr1, pv0, pv1, pv2, pv3;
    pn0 = *(const bf16x8*)(Kbh + (size_t)(kn_r) * 128 + kn_c);
    pn1 = *(const bf16x8*)(Kbh + (size_t)(kn_r + 16) * 128 + kn_c);
    pn2 = *(const bf16x8*)(Kbh + (size_t)(kn_r + 32) * 128 + kn_c);
    pn3 = *(const bf16x8*)(Kbh + (size_t)(kn_r + 48) * 128 + kn_c);
    pr0 = *(const bf16x8*)(krb + (size_t)(kr_r) * 64 + kr_c);
    pr1 = *(const bf16x8*)(krb + (size_t)(kr_r + 32) * 64 + kr_c);
    pv0 = *(const bf16x8*)(Vbh + (size_t)(v_d) * 2048 + v_c);
    pv1 = *(const bf16x8*)(Vbh + (size_t)(v_d + 32) * 2048 + v_c);
    pv2 = *(const bf16x8*)(Vbh + (size_t)(v_d + 64) * 2048 + v_c);
    pv3 = *(const bf16x8*)(Vbh + (size_t)(v_d + 96) * 2048 + v_c);

    for (int kt = 0; kt < kend; kt += 64) {
      // write prefetched tile to LDS
      *(bf16x8*)(Ks + (kn_r) * 196 + kn_c) = pn0;
      *(bf16x8*)(Ks + (kn_r + 16) * 196 + kn_c) = pn1;
      *(bf16x8*)(Ks + (kn_r + 32) * 196 + kn_c) = pn2;
      *(bf16x8*)(Ks + (kn_r + 48) * 196 + kn_c) = pn3;
      *(bf16x8*)(Ks + (kr_r) * 196 + 128 + kr_c) = pr0;
      *(bf16x8*)(Ks + (kr_r + 32) * 196 + 128 + kr_c) = pr1;
      *(bf16x8*)(Vs + (v_d) * 70 + v_c) = pv0;
      *(bf16x8*)(Vs + (v_d + 32) * 70 + v_c) = pv1;
      *(bf16x8*)(Vs + (v_d + 64) * 70 + v_c) = pv2;
      *(bf16x8*)(Vs + (v_d + 96) * 70 + v_c) = pv3;
      __syncthreads();
      // issue NEXT tile's loads — fly under this tile's compute.
      if (kt + 64 < kend) {
        int k2 = kt + 64;
        pn0 = *(const bf16x8*)(Kbh + (size_t)(k2 + kn_r) * 128 + kn_c);
        pn1 = *(const bf16x8*)(Kbh + (size_t)(k2 + kn_r + 16) * 128 + kn_c);
        pn2 = *(const bf16x8*)(Kbh + (size_t)(k2 + kn_r + 32) * 128 + kn_c);
        pn3 = *(const bf16x8*)(Kbh + (size_t)(k2 + kn_r + 48) * 128 + kn_c);
        pr0 = *(const bf16x8*)(krb + (size_t)(k2 + kr_r) * 64 + kr_c);
        pr1 = *(const bf16x8*)(krb + (size_t)(k2 + kr_r + 32) * 64 + kr_c);
        pv0 = *(const bf16x8*)(Vbh + (size_t)(v_d) * 2048 + k2 + v_c);
        pv1 = *(const bf16x8*)(Vbh + (size_t)(v_d + 32) * 2048 + k2 + v_c);
        pv2 = *(const bf16x8*)(Vbh + (size_t)(v_d + 64) * 2048 + k2 + v_c);
        pv3 = *(const bf16x8*)(Vbh + (size_t)(v_d + 96) * 2048 + k2 + v_c);
      }

      // S^T: A = K rows, B = Q cols
      f32x4 s[4] = {};
      __builtin_amdgcn_s_setprio(1);
#pragma unroll
      for (int kk = 0; kk < 6; ++kk) {
#pragma unroll
        for (int c = 0; c < 4; ++c) {
          bf16x8 kf = *(const bf16x8*)(Ks + (c * 16 + l15) * 196 + kk * 32 + l4 * 8);
          s[c] = __builtin_amdgcn_mfma_f32_16x16x32_bf16(kf, qf[kk], s[c], 0, 0, 0);
        }
      }
      __builtin_amdgcn_s_setprio(0);

      if (kt == q0) {  // diagonal tile: mask k > q
#pragma unroll
        for (int c = 0; c < 4; ++c)
#pragma unroll
          for (int r = 0; r < 4; ++r) {
            int k = kt + c * 16 + l4 * 4 + r;
            if (k > qcol) s[c][r] = -1e30f;
          }
      }
      // per-q softmax: in-lane over 16 + cross-group (xor 16, 32)
      float mx = fmaxf(fmaxf(fmaxf(s[0][0], s[0][1]), fmaxf(s[0][2], s[0][3])),
                       fmaxf(fmaxf(s[1][0], s[1][1]), fmaxf(s[1][2], s[1][3])));
      mx = fmaxf(mx, fmaxf(fmaxf(fmaxf(s[2][0], s[2][1]), fmaxf(s[2][2], s[2][3])),
                           fmaxf(fmaxf(s[3][0], s[3][1]), fmaxf(s[3][2], s[3][3]))));
      mx = fmaxf(mx, __shfl_xor(mx, 16));
      mx = fmaxf(mx, __shfl_xor(mx, 32));
      float newm = fmaxf(m_i, mx);
      float alpha = __builtin_amdgcn_exp2f(m_i - newm);
      float rs = 0.f;
#pragma unroll
      for (int c = 0; c < 4; ++c)
#pragma unroll
        for (int r = 0; r < 4; ++r) {
          float p = __builtin_amdgcn_exp2f(s[c][r] - newm);
          s[c][r] = p; rs += p;
        }
      rs += __shfl_xor(rs, 16);
      rs += __shfl_xor(rs, 32);
      l_i = l_i * alpha + rs;
      m_i = newm;
#pragma unroll
      for (int dt = 0; dt < 8; ++dt)
#pragma unroll
        for (int r = 0; r < 4; ++r) oaccT[dt][r] *= alpha;

      // pack P^T to bf16 pairs (named regs; no runtime indexing)
      u32 pk00 = pk2(s[0][0], s[0][1]), pk01 = pk2(s[0][2], s[0][3]);
      u32 pk10 = pk2(s[1][0], s[1][1]), pk11 = pk2(s[1][2], s[1][3]);
      u32 pk20 = pk2(s[2][0], s[2][1]), pk21 = pk2(s[2][2], s[2][3]);
      u32 pk30 = pk2(s[3][0], s[3][1]), pk31 = pk2(s[3][2], s[3][3]);
      union { bf16x8 v; u32 u[4]; } P0, P1;
      {
        u32 a0 = __builtin_amdgcn_ds_bpermute(sA, (int)pk00);
        u32 a1 = __builtin_amdgcn_ds_bpermute(sA, (int)pk01);
        u32 a2 = __builtin_amdgcn_ds_bpermute(sB, (int)pk00);
        u32 a3 = __builtin_amdgcn_ds_bpermute(sB, (int)pk01);
        u32 b0 = __builtin_amdgcn_ds_bpermute(sA, (int)pk10);
        u32 b1 = __builtin_amdgcn_ds_bpermute(sA, (int)pk11);
        u32 b2 = __builtin_amdgcn_ds_bpermute(sB, (int)pk10);
        u32 b3 = __builtin_amdgcn_ds_bpermute(sB, (int)pk11);
        P0.u[0] = chi ? b0 : a0; P0.u[1] = chi ? b1 : a1;
        P0.u[2] = chi ? b2 : a2; P0.u[3] = chi ? b3 : a3;
      }
      {
        u32 a0 = __builtin_amdgcn_ds_bpermute(sA, (int)pk20);
        u32 a1 = __builtin_amdgcn_ds_bpermute(sA, (int)pk21);
        u32 a2 = __builtin_amdgcn_ds_bpermute(sB, (int)pk20);
        u32 a3 = __builtin_amdgcn_ds_bpermute(sB, (int)pk21);
        u32 b0 = __builtin_amdgcn_ds_bpermute(sA, (int)pk30);
        u32 b1 = __builtin_amdgcn_ds_bpermute(sA, (int)pk31);
        u32 b2 = __builtin_amdgcn_ds_bpermute(sB, (int)pk30);
        u32 b3 = __builtin_amdgcn_ds_bpermute(sB, (int)pk31);
        P1.u[0] = chi ? b0 : a0; P1.u[1] = chi ? b1 : a1;
        P1.u[2] = chi ? b2 : a2; P1.u[3] = chi ? b3 : a3;
      }

      // O^T += V^T-frag x P^T-frag
      __builtin_amdgcn_s_setprio(1);
#pragma unroll
      for (int dt = 0; dt < 8; ++dt) {
        bf16x8 vf0 = *(const bf16x8*)(Vs + (dt * 16 + l15) * 70 + l4 * 8);
        bf16x8 vf1 = *(const bf16x8*)(Vs + (dt * 16 + l15) * 70 + 32 + l4 * 8);
        oaccT[dt] = __builtin_amdgcn_mfma_f32_16x16x32_bf16(vf0, P0.v, oaccT[dt], 0, 0, 0);
        oaccT[dt] = __builtin_amdgcn_mfma_f32_16x16x32_bf16(vf1, P1.v, oaccT[dt], 0, 0, 0);
      }
      __builtin_amdgcn_s_setprio(0);
      __syncthreads();
    }
    // epilogue: lane holds O^T[d = dt*16 + l4*4 + r][q = qcol]
    float inv = 1.0f / l_i;
    short* dst = ob + ((size_t)(b * 2048 + qcol)) * 2048 + h * 128;
#pragma unroll
    for (int dt = 0; dt < 8; ++dt) {
      uint2 o;
      o.x = pk2(oaccT[dt][0] * inv, oaccT[dt][1] * inv);
      o.y = pk2(oaccT[dt][2] * inv, oaccT[dt][3] * inv);
      *(uint2*)(dst + dt * 16 + l4 * 4) = o;
    }
  }
}

// ---------------------------------------------------------------------------
extern "C" void kernel_launch(void* const* d_in, const int* in_sizes, int n_in,
                              void* d_out, int out_size, void* d_ws, size_t ws_size,
                              hipStream_t stream) {
  const float* x    = (const float*)d_in[0];
  const float* fcos = (const float*)d_in[1];
  const float* fsin = (const float*)d_in[2];
  const float* Wqd  = (const float*)d_in[3];
  const float* qnw  = (const float*)d_in[4];
  const float* Wqu  = (const float*)d_in[5];
  const float* Wkvd = (const float*)d_in[6];
  const float* kvnw = (const float*)d_in[7];
  const float* Wkvu = (const float*)d_in[8];
  const float* Wo   = (const float*)d_in[9];
  const float* bo   = (const float*)d_in[10];
  float* out = (float*)d_out;
  char* ws = (char*)d_ws;

  short* x_bf  = (short*)(ws + 0);           // 4096x2048 bf16
  short* w_cat = (short*)(ws + 16777216);    // 2176x2048 (Wqd;Wkvd pad)
  short* w_qu  = (short*)(ws + 25690112);    // 3072x1536
  short* w_kvu = (short*)(ws + 35127296);    // 4096x512
  short* w_o   = (short*)(ws + 39321600);    // 2048x2048
  short* c1    = (short*)(ws + 47710208);    // 4096x2176 bf16 (qdown|krope|ckv)
  short* qn    = (short*)(ws + 65536000);    // 4096x1536 bf16
  short* ckvn  = (short*)(ws + 78118912);    // 4096x512 bf16
  short* q_b   = (short*)(ws + 82313216);    // (B,H,S,192) bf16
  short* k_b   = (short*)(ws + 107479040);   // (B,H,S,128) bf16 (nope only)
  short* vT    = (short*)(ws + 132644864);   // (B,H,128,S) bf16
  short* o_bf  = (short*)(ws + 149422080);   // (B,S,2048) bf16
  short* kr    = (short*)(ws + 166199296);   // (B,S,64) bf16 roped shared k

  f2bf_all_kernel<<<23296, 256, 0, stream>>>(x, x_bf, Wqd, w_cat, Wqu, w_qu,
                                             Wkvu, w_kvu, Wo, w_o,
                                             Wkvd, w_cat + 1536 * 2048);

  gemm_bt<1><<<dim3(17, 32), 256, 0, stream>>>(x_bf, w_cat, c1, nullptr, 2048, 2176,
                                               nullptr, nullptr, nullptr);
  norm_krope_kernel<<<2560, 256, 0, stream>>>(c1, qnw, qn, kvnw, ckvn,
                                              fcos, fsin, kr);

  gemm_up<<<1792, 256, 0, stream>>>(qn, w_qu, q_b, ckvn, w_kvu, k_b, vT,
                                    fcos, fsin);

  attn_kernel<<<512, 256, 0, stream>>>(q_b, k_b, kr, vT, o_bf);

  gemm_bt<0><<<dim3(16, 32), 256, 0, stream>>>(o_bf, w_o, out, bo, 2048, 2048,
                                               nullptr, nullptr, nullptr);
}